// Round 10
// baseline (235.111 us; speedup 1.0000x reference)
//
#include <hip/hip_runtime.h>
#include <hip/hip_bf16.h>

// ---------------- problem constants ----------------
#define D_MODEL   1024
#define N_HEADS   16
#define D_LATENT  256
#define HEAD_DIM  64
#define SEQ_T     4096
#define BATCH     4
#define M_TOK     (BATCH * SEQ_T)   // 16384

typedef __attribute__((ext_vector_type(8))) short          short8;
typedef __attribute__((ext_vector_type(4))) float          f32x4;
typedef __attribute__((ext_vector_type(8))) unsigned short u16x8;

static __device__ __forceinline__ float b2f(unsigned short u) {
  unsigned x = ((unsigned)u) << 16;
  float f;
  __builtin_memcpy(&f, &x, 4);
  return f;
}
static __device__ __forceinline__ unsigned short f2b(float f) {
  unsigned x;
  __builtin_memcpy(&x, &f, 4);
  x += 0x7fffu + ((x >> 16) & 1u);   // round-to-nearest-even
  return (unsigned short)(x >> 16);
}

static __device__ __forceinline__ void gload_lds16(const unsigned short* g, unsigned short* l) {
  __builtin_amdgcn_global_load_lds(
      (const __attribute__((address_space(1))) unsigned int*)g,
      (__attribute__((address_space(3))) unsigned int*)l, 16, 0, 0);
}

#define BAR()    __builtin_amdgcn_s_barrier()
#define LGKM0()  asm volatile("s_waitcnt lgkmcnt(0)" ::: "memory")
#define LGKM8()  asm volatile("s_waitcnt lgkmcnt(8)" ::: "memory")
#define VMCNT6() asm volatile("s_waitcnt vmcnt(6)" ::: "memory")
#define VMCNT0() asm volatile("s_waitcnt vmcnt(0)" ::: "memory")

// ---------------- RoPE cos/sin table: [t][j] j<32, float2{cos,sin} ----------------
__global__ void rope_tab_kernel(float2* __restrict__ tab) {
  int idx = blockIdx.x * blockDim.x + threadIdx.x;
  if (idx >= SEQ_T * 32) return;
  int t = idx >> 5, j = idx & 31;
  float invf = powf(10000.f, -(float)j * (1.f / 32.f));
  float ang = (float)t * invf;
  float s, c;
  sincosf(ang, &s, &c);
  tab[idx] = make_float2(c, s);
}

// ---------------- transpose + convert: src f32 KxN -> dst bf16 NxK ----------------
__global__ __launch_bounds__(256) void tconv_kernel(const float* __restrict__ src,
                                                    unsigned short* __restrict__ dst,
                                                    int K, int N) {
  __shared__ float tile[32][33];
  const int tx = threadIdx.x & 31, ty = threadIdx.x >> 5;  // ty 0..7
  const int nb = blockIdx.x * 32, kb = blockIdx.y * 32;
#pragma unroll
  for (int j = 0; j < 4; ++j)
    tile[ty + 8 * j][tx] = src[(size_t)(kb + ty + 8 * j) * N + nb + tx];
  __syncthreads();
#pragma unroll
  for (int j = 0; j < 4; ++j)
    dst[(size_t)(nb + ty + 8 * j) * K + kb + tx] = f2b(tile[tx][ty + 8 * j]);
}

// =====================================================================
// gemm_bt: 128x128-tile GEMM, 4 waves, BK=64, 2-barrier loop (m97 structure).
// AF32: A source is f32 (x) — reg-staged with fused f32->bf16 conversion
//   (2x float4 at the SAME pre-swizzled granule offsets as the gload path,
//    __float22bfloat162_rn pairs, ds_write_b128 to linear flatB — swizzle
//    involution preserved, rule #21). Kills the separate cvt kernel + Xb.
// EPI 4 = FUSED Q|latent: colB<1024 -> RoPE -> Cout (Qb, stride 1024),
//         colB>=1024 -> plain+bias2 -> Cout2 (Lb, stride 256, col-1024).
// Epilogue = r8 scatter version (r9 LDS-bounce was neutral + bank conflicts).
// =====================================================================
template <int EPI, bool AF32>
__global__ __launch_bounds__(256) void gemm_bt(const void* __restrict__ Ain,
                                               const unsigned short* __restrict__ Bt,
                                               const float* __restrict__ bias,
                                               void* __restrict__ Cout,
                                               const float2* __restrict__ tab,
                                               int M, int N, int K,
                                               const float* __restrict__ bias2,
                                               void* __restrict__ Cout2) {
  __shared__ unsigned short As[128 * 64];
  __shared__ unsigned short Bs[128 * 64];
  const int tid = threadIdx.x;
  const int lane = tid & 63;
  const int wid = tid >> 6;
  const int wr = wid >> 1, wc = wid & 1;
  const int l15 = lane & 15, kg = lane >> 4;

  const int gx = N >> 7;
  const int nwg = gridDim.x;
  const int q8 = nwg >> 3;
  const int bid = blockIdx.x;
  const int sid = (bid & 7) * q8 + (bid >> 3);
  const int bx = sid % gx;
  const int by = sid / gx;
  const long mBase = (long)by * 128;
  const long nBase = (long)bx * 128;

  f32x4 acc[4][4];
#pragma unroll
  for (int m = 0; m < 4; ++m)
#pragma unroll
    for (int n = 0; n < 4; ++n) {
      acc[m][n][0] = 0.f; acc[m][n][1] = 0.f; acc[m][n][2] = 0.f; acc[m][n][3] = 0.f;
    }

  for (int kt = 0; kt < K; kt += 64) {
#pragma unroll
    for (int i = 0; i < 4; ++i) {
      const int flatB = i * 4096 + tid * 16;
      const int row = flatB >> 7;
      const int kb = (flatB & 127) ^ ((row & 7) << 4);
      gload_lds16(Bt + (size_t)(nBase + row) * K + kt + (kb >> 1),
                  (unsigned short*)((char*)Bs + flatB));
    }
    if constexpr (AF32) {
      const float* Af = (const float*)Ain;
#pragma unroll
      for (int i = 0; i < 4; ++i) {
        const int flatB = i * 4096 + tid * 16;
        const int row = flatB >> 7;
        const int kb = (flatB & 127) ^ ((row & 7) << 4);
        const float4* src = (const float4*)(Af + (size_t)(mBase + row) * K + kt + (kb >> 1));
        const float4 v0 = src[0], v1 = src[1];
        union { __hip_bfloat162 h[4]; u16x8 v; } o;
        o.h[0] = __float22bfloat162_rn(make_float2(v0.x, v0.y));
        o.h[1] = __float22bfloat162_rn(make_float2(v0.z, v0.w));
        o.h[2] = __float22bfloat162_rn(make_float2(v1.x, v1.y));
        o.h[3] = __float22bfloat162_rn(make_float2(v1.z, v1.w));
        *(u16x8*)((char*)As + flatB) = o.v;
      }
    } else {
      const unsigned short* Ab16 = (const unsigned short*)Ain;
#pragma unroll
      for (int i = 0; i < 4; ++i) {
        const int flatB = i * 4096 + tid * 16;
        const int row = flatB >> 7;
        const int kb = (flatB & 127) ^ ((row & 7) << 4);
        gload_lds16(Ab16 + (size_t)(mBase + row) * K + kt + (kb >> 1),
                    (unsigned short*)((char*)As + flatB));
      }
    }
    __syncthreads();
#pragma unroll
    for (int ks = 0; ks < 2; ++ks) {
      short8 af[4], bfr[4];
      const int koff = ks * 64 + kg * 16;
#pragma unroll
      for (int m = 0; m < 4; ++m) {
        const int row = wr * 64 + m * 16 + l15;
        af[m] = *(const short8*)((const char*)As + row * 128 + (koff ^ ((row & 7) << 4)));
      }
#pragma unroll
      for (int n = 0; n < 4; ++n) {
        const int row = wc * 64 + n * 16 + l15;
        bfr[n] = *(const short8*)((const char*)Bs + row * 128 + (koff ^ ((row & 7) << 4)));
      }
#pragma unroll
      for (int m = 0; m < 4; ++m)
#pragma unroll
        for (int n = 0; n < 4; ++n)
          acc[m][n] = __builtin_amdgcn_mfma_f32_16x16x32_bf16(af[m], bfr[n], acc[m][n], 0, 0, 0);
    }
    __syncthreads();
  }

  // ---------------- epilogue (r8 scatter version) ----------------
  const int colB = (int)nBase + wc * 64;
  const long rowB = mBase + (long)wr * 64;
  const bool doRope = (EPI == 1) || (EPI == 2 && (((colB >> 6) & 1) == 0)) ||
                      (EPI == 4 && colB < 1024);

  if (doRope) {
    const int cstride = (EPI == 4) ? 1024 : N;
#pragma unroll
    for (int p = 0; p < 2; ++p) {
      const int c1 = colB + p * 16 + l15;
      const int c2 = c1 + 32;
      const float b1 = bias[c1], b2 = bias[c2];
      const int j = p * 16 + l15;  // freq index 0..31 (colB is 64-aligned)
#pragma unroll
      for (int m = 0; m < 4; ++m) {
#pragma unroll
        for (int i = 0; i < 4; ++i) {
          const long row = rowB + m * 16 + kg * 4 + i;
          const int tt = (int)(row & (SEQ_T - 1));
          const float2 cs = tab[tt * 32 + j];
          const float x1 = acc[m][p][i] + b1;
          const float x2 = acc[m][p + 2][i] + b2;
          ((unsigned short*)Cout)[row * cstride + c1] = f2b(x1 * cs.x - x2 * cs.y);
          ((unsigned short*)Cout)[row * cstride + c2] = f2b(x1 * cs.y + x2 * cs.x);
        }
      }
    }
  } else if (EPI == 4) {
    // latent rows of the fused GEMM -> Lb, stride 256
#pragma unroll
    for (int n = 0; n < 4; ++n) {
      const int col = colB + n * 16 + l15 - 1024;
      const float bb = bias2[col];
#pragma unroll
      for (int m = 0; m < 4; ++m) {
#pragma unroll
        for (int i = 0; i < 4; ++i) {
          const long row = rowB + m * 16 + kg * 4 + i;
          ((unsigned short*)Cout2)[row * 256 + col] = f2b(acc[m][n][i] + bb);
        }
      }
    }
  } else {
#pragma unroll
    for (int n = 0; n < 4; ++n) {
      const int col = colB + n * 16 + l15;
      const float bb = bias[col];
#pragma unroll
      for (int m = 0; m < 4; ++m) {
#pragma unroll
        for (int i = 0; i < 4; ++i) {
          const long row = rowB + m * 16 + kg * 4 + i;
          ((unsigned short*)Cout)[row * N + col] = f2b(acc[m][n][i] + bb);
        }
      }
    }
  }
  (void)M;
}

// =====================================================================
// gemm8p (r5 version): 256x256, 8 waves, BK=64, 8-phase counted-vmcnt.
// EPI: 2 = RoPE even 64-col blocks (K of KV), bf16 out; 3 = f32 out.
// =====================================================================
template <int EPI, int NN, int KK>
__global__ __launch_bounds__(512) void gemm8p(const unsigned short* __restrict__ A,
                                              const unsigned short* __restrict__ Bt,
                                              const float* __restrict__ bias,
                                              void* __restrict__ Cout,
                                              const float2* __restrict__ tab) {
  __shared__ unsigned short As[2][16384];
  __shared__ unsigned short Bs[2][16384];
  const int tid = threadIdx.x;
  const int lane = tid & 63;
  const int wid = tid >> 6;
  const int wm = wid >> 2;
  const int wn = wid & 3;
  const int l15 = lane & 15, kg = lane >> 4;

  constexpr int gx = NN >> 8;
  const int q8 = (int)gridDim.x >> 3;
  const int bid = (int)blockIdx.x;
  const int sid = (bid & 7) * q8 + (bid >> 3);
  const long mBase = (long)(sid / gx) * 256;
  const long nBase = (long)(sid % gx) * 256;

  constexpr int nt = KK >> 6;

  const int r0 = tid >> 3;
  const int cb = (tid & 7) * 16;
  const int scb = cb ^ ((r0 & 7) << 4);
  const unsigned short* gA = A + (mBase + r0) * KK + (scb >> 1);
  const unsigned short* gB = Bt + (nBase + r0) * KK + (scb >> 1);
  const int dOff = tid << 3;

  auto stA = [&](int h, int t, int buf) __attribute__((always_inline)) {
#pragma unroll
    for (int j = 0; j < 2; ++j)
      gload_lds16(gA + (size_t)(h * 128 + j * 64) * KK + t * 64,
                  &As[buf][h * 8192 + j * 4096 + dOff]);
  };
  auto stB = [&](int h, int t, int buf) __attribute__((always_inline)) {
#pragma unroll
    for (int j = 0; j < 2; ++j)
      gload_lds16(gB + (size_t)(h * 128 + j * 64) * KK + t * 64,
                  &Bs[buf][h * 8192 + j * 4096 + dOff]);
  };

  f32x4 acc[8][4];
#pragma unroll
  for (int m = 0; m < 8; ++m)
#pragma unroll
    for (int n = 0; n < 4; ++n) {
      acc[m][n][0] = 0.f; acc[m][n][1] = 0.f; acc[m][n][2] = 0.f; acc[m][n][3] = 0.f;
    }

  stA(0, 0, 0); stA(1, 0, 0); stB(0, 0, 0); stB(1, 0, 0);
  stB(0, 1, 1); stB(1, 1, 1); stA(0, 1, 1);
  VMCNT6();
  BAR();

  auto ktile = [&](int t, int cur) __attribute__((always_inline)) {
    const char* sa = (const char*)&As[cur][0];
    const char* sb = (const char*)&Bs[cur][0];
    short8 a[4][2], b[4][2];

    // phase 0
#pragma unroll
    for (int m = 0; m < 4; ++m) {
      const int row = wm * 128 + m * 16 + l15, sw = (row & 7) << 4;
      a[m][0] = *(const short8*)(sa + row * 128 + ((kg * 16) ^ sw));
      a[m][1] = *(const short8*)(sa + row * 128 + ((64 + kg * 16) ^ sw));
    }
#pragma unroll
    for (int n = 0; n < 2; ++n) {
      const int row = wn * 64 + n * 16 + l15, sw = (row & 7) << 4;
      b[n][0] = *(const short8*)(sb + row * 128 + ((kg * 16) ^ sw));
      b[n][1] = *(const short8*)(sb + row * 128 + ((64 + kg * 16) ^ sw));
    }
    if (t + 1 < nt) stA(1, t + 1, cur ^ 1);
    LGKM8();
    BAR(); LGKM0();
    __builtin_amdgcn_s_setprio(1);
#pragma unroll
    for (int m = 0; m < 4; ++m)
#pragma unroll
      for (int n = 0; n < 2; ++n) {
        acc[m][n] = __builtin_amdgcn_mfma_f32_16x16x32_bf16(a[m][0], b[n][0], acc[m][n], 0, 0, 0);
        acc[m][n] = __builtin_amdgcn_mfma_f32_16x16x32_bf16(a[m][1], b[n][1], acc[m][n], 0, 0, 0);
      }
    __builtin_amdgcn_s_setprio(0);
    BAR();

    // phase 1
#pragma unroll
    for (int n = 2; n < 4; ++n) {
      const int row = wn * 64 + n * 16 + l15, sw = (row & 7) << 4;
      b[n][0] = *(const short8*)(sb + row * 128 + ((kg * 16) ^ sw));
      b[n][1] = *(const short8*)(sb + row * 128 + ((64 + kg * 16) ^ sw));
    }
    BAR(); LGKM0();
    __builtin_amdgcn_s_setprio(1);
#pragma unroll
    for (int m = 0; m < 4; ++m)
#pragma unroll
      for (int n = 2; n < 4; ++n) {
        acc[m][n] = __builtin_amdgcn_mfma_f32_16x16x32_bf16(a[m][0], b[n][0], acc[m][n], 0, 0, 0);
        acc[m][n] = __builtin_amdgcn_mfma_f32_16x16x32_bf16(a[m][1], b[n][1], acc[m][n], 0, 0, 0);
      }
    __builtin_amdgcn_s_setprio(0);
    BAR();

    // phase 2
#pragma unroll
    for (int m = 0; m < 4; ++m) {
      const int row = wm * 128 + (m + 4) * 16 + l15, sw = (row & 7) << 4;
      a[m][0] = *(const short8*)(sa + row * 128 + ((kg * 16) ^ sw));
      a[m][1] = *(const short8*)(sa + row * 128 + ((64 + kg * 16) ^ sw));
    }
    if (t + 2 < nt) stB(0, t + 2, cur);
    BAR(); LGKM0();
    __builtin_amdgcn_s_setprio(1);
#pragma unroll
    for (int m = 0; m < 4; ++m)
#pragma unroll
      for (int n = 2; n < 4; ++n) {
        acc[m + 4][n] = __builtin_amdgcn_mfma_f32_16x16x32_bf16(a[m][0], b[n][0], acc[m + 4][n], 0, 0, 0);
        acc[m + 4][n] = __builtin_amdgcn_mfma_f32_16x16x32_bf16(a[m][1], b[n][1], acc[m + 4][n], 0, 0, 0);
      }
    __builtin_amdgcn_s_setprio(0);
    BAR();

    // phase 3
    if (t + 2 < nt) {
      stB(1, t + 2, cur);
      stA(0, t + 2, cur);
      VMCNT6();
    } else if (t + 1 < nt) {
      VMCNT0();
    }
    BAR();
    __builtin_amdgcn_s_setprio(1);
#pragma unroll
    for (int m = 0; m < 4; ++m)
#pragma unroll
      for (int n = 0; n < 2; ++n) {
        acc[m + 4][n] = __builtin_amdgcn_mfma_f32_16x16x32_bf16(a[m][0], b[n][0], acc[m + 4][n], 0, 0, 0);
        acc[m + 4][n] = __builtin_amdgcn_mfma_f32_16x16x32_bf16(a[m][1], b[n][1], acc[m + 4][n], 0, 0, 0);
      }
    __builtin_amdgcn_s_setprio(0);
    BAR();
  };

#pragma unroll 1
  for (int t = 0; t < nt; t += 2) {
    ktile(t, 0);
    ktile(t + 1, 1);
  }

  // epilogue
  const long rowB = mBase + (long)wm * 128;
  const int colB = (int)nBase + wn * 64;
  const bool doRope = (EPI == 2 && (((colB >> 6) & 1) == 0));

  if (doRope) {
#pragma unroll
    for (int p = 0; p < 2; ++p) {
      const int c1 = colB + p * 16 + l15;
      const int c2 = c1 + 32;
      const float b1 = bias[c1], b2 = bias[c2];
      const int j = p * 16 + l15;
#pragma unroll
      for (int m = 0; m < 8; ++m) {
#pragma unroll
        for (int i = 0; i < 4; ++i) {
          const long row = rowB + m * 16 + kg * 4 + i;
          const int tt = (int)(row & (SEQ_T - 1));
          const float2 cs = tab[tt * 32 + j];
          const float x1 = acc[m][p][i] + b1;
          const float x2 = acc[m][p + 2][i] + b2;
          ((unsigned short*)Cout)[row * NN + c1] = f2b(x1 * cs.x - x2 * cs.y);
          ((unsigned short*)Cout)[row * NN + c2] = f2b(x1 * cs.y + x2 * cs.x);
        }
      }
    }
  } else {
#pragma unroll
    for (int n = 0; n < 4; ++n) {
      const int col = colB + n * 16 + l15;
      const float bb = bias[col];
#pragma unroll
      for (int m = 0; m < 8; ++m) {
#pragma unroll
        for (int i = 0; i < 4; ++i) {
          const long row = rowB + m * 16 + kg * 4 + i;
          const float v = acc[m][n][i] + bb;
          if (EPI == 3)
            ((float*)Cout)[row * NN + col] = v;
          else
            ((unsigned short*)Cout)[row * NN + col] = f2b(v);
        }
      }
    }
  }
  (void)tab;
}

// ---------------- per-token head-vs-head attention ----------------
__global__ __launch_bounds__(256) void attn_kernel(const unsigned short* __restrict__ Qb,
                                                   const unsigned short* __restrict__ KVb,
                                                   unsigned short* __restrict__ Ab) {
  __shared__ float sm[4 * 3 * 16 * 68];
  const int tid = threadIdx.x;
  const int w = tid >> 6, lane = tid & 63;
  const long token = (long)blockIdx.x * 4 + w;
  float* qs = &sm[w * (3 * 16 * 68)];
  float* ks = qs + 16 * 68;
  float* vs = ks + 16 * 68;

  {
    const u16x8* qg = (const u16x8*)(Qb + token * 1024 + lane * 16);
    u16x8 a0 = qg[0], a1 = qg[1];
    const int h = lane >> 2, d0 = (lane & 3) * 16;
    float tmp[16];
#pragma unroll
    for (int j = 0; j < 8; ++j) { tmp[j] = b2f(a0[j]); tmp[8 + j] = b2f(a1[j]); }
    float4* dst = (float4*)&qs[h * 68 + d0];
#pragma unroll
    for (int v = 0; v < 4; ++v) dst[v] = *(float4*)&tmp[4 * v];
  }
  {
    const u16x8* kg = (const u16x8*)(KVb + token * 2048 + lane * 32);
    u16x8 c0 = kg[0], c1 = kg[1], c2 = kg[2], c3 = kg[3];
    const int h = lane >> 2, part = lane & 3;
    float tmp[32];
#pragma unroll
    for (int j = 0; j < 8; ++j) {
      tmp[j] = b2f(c0[j]); tmp[8 + j] = b2f(c1[j]);
      tmp[16 + j] = b2f(c2[j]); tmp[24 + j] = b2f(c3[j]);
    }
    float* dst = (part < 2) ? &ks[h * 68 + part * 32] : &vs[h * 68 + (part - 2) * 32];
    float4* d4 = (float4*)dst;
#pragma unroll
    for (int v = 0; v < 8; ++v) d4[v] = *(float4*)&tmp[4 * v];
  }
  __syncthreads();

  const int h = lane >> 2, b = lane & 3;
  float s[4];
#pragma unroll
  for (int a = 0; a < 4; ++a) {
    const int g = 4 * a + b;
    const float4* qr = (const float4*)&qs[h * 68];
    const float4* kr = (const float4*)&ks[g * 68];
    float accv = 0.f;
#pragma unroll
    for (int t = 0; t < 16; ++t) {
      float4 qv = qr[t], kv = kr[t];
      accv += qv.x * kv.x + qv.y * kv.y + qv.z * kv.z + qv.w * kv.w;
    }
    s[a] = accv * 0.125f;
  }
  float mx = fmaxf(fmaxf(s[0], s[1]), fmaxf(s[2], s[3]));
  mx = fmaxf(mx, __shfl_xor(mx, 1, 64));
  mx = fmaxf(mx, __shfl_xor(mx, 2, 64));
  float e[4], sum = 0.f;
#pragma unroll
  for (int a = 0; a < 4; ++a) { e[a] = __expf(s[a] - mx); sum += e[a]; }
  sum += __shfl_xor(sum, 1, 64);
  sum += __shfl_xor(sum, 2, 64);
  const float rinv = 1.f / sum;
  float p[4];
#pragma unroll
  for (int a = 0; a < 4; ++a) p[a] = e[a] * rinv;

  float pf[16];
  const int qbase = lane & ~3;
#pragma unroll
  for (int bb = 0; bb < 4; ++bb)
#pragma unroll
    for (int a = 0; a < 4; ++a) pf[4 * a + bb] = __shfl(p[a], qbase + bb, 64);

#pragma unroll
  for (int k16 = 0; k16 < 16; ++k16) {
    const int d = b + 4 * k16;
    float o = 0.f;
#pragma unroll
    for (int g = 0; g < 16; ++g) o += pf[g] * vs[g * 68 + d];
    Ab[token * 1024 + h * 64 + d] = f2b(o);
  }
}

// ---------------- workspace layout (bytes) ----------------
#define OFF_TAB  0UL
#define OFF_AB   1048576UL       // attention output (bf16, 33.5MB) — was Xb region
#define OFF_WQT  34603008UL      // WqT (1024x1024) ...
#define OFF_WDT  36700160UL      // ... contiguous with WdT (256x1024): fused 1280xK B
#define OFF_WUT  37224448UL
#define OFF_WOT  38273024UL
#define OFF_QB   40370176UL
#define OFF_LB   73924608UL
#define OFF_KVB  82313216UL
#define WS_NEEDED 149422080UL

extern "C" void kernel_launch(void* const* d_in, const int* in_sizes, int n_in,
                              void* d_out, int out_size, void* d_ws, size_t ws_size,
                              hipStream_t stream) {
  (void)in_sizes; (void)n_in; (void)out_size;
  if (ws_size < WS_NEEDED) return;

  const float* x     = (const float*)d_in[0];
  const float* Wq    = (const float*)d_in[1];
  const float* bq    = (const float*)d_in[2];
  const float* Wdown = (const float*)d_in[3];
  const float* bdown = (const float*)d_in[4];
  const float* Wup   = (const float*)d_in[5];
  const float* bup   = (const float*)d_in[6];
  const float* Wout  = (const float*)d_in[7];
  const float* bout  = (const float*)d_in[8];

  char* ws = (char*)d_ws;
  float2*         tab = (float2*)(ws + OFF_TAB);
  unsigned short* Ab  = (unsigned short*)(ws + OFF_AB);
  unsigned short* WqT = (unsigned short*)(ws + OFF_WQT);
  unsigned short* WdT = (unsigned short*)(ws + OFF_WDT);
  unsigned short* WuT = (unsigned short*)(ws + OFF_WUT);
  unsigned short* WoT = (unsigned short*)(ws + OFF_WOT);
  unsigned short* Qb  = (unsigned short*)(ws + OFF_QB);
  unsigned short* Lb  = (unsigned short*)(ws + OFF_LB);
  unsigned short* KVb = (unsigned short*)(ws + OFF_KVB);

  rope_tab_kernel<<<(SEQ_T * 32 + 255) / 256, 256, 0, stream>>>(tab);
  tconv_kernel<<<dim3(D_MODEL / 32, D_MODEL / 32), 256, 0, stream>>>(Wq, WqT, D_MODEL, D_MODEL);
  tconv_kernel<<<dim3(D_LATENT / 32, D_MODEL / 32), 256, 0, stream>>>(Wdown, WdT, D_MODEL, D_LATENT);
  tconv_kernel<<<dim3(2 * D_MODEL / 32, D_LATENT / 32), 256, 0, stream>>>(Wup, WuT, D_LATENT, 2 * D_MODEL);
  tconv_kernel<<<dim3(D_MODEL / 32, D_MODEL / 32), 256, 0, stream>>>(Wout, WoT, D_MODEL, D_MODEL);

  // G1: fused [Q | latent] = x(f32, converted in-staging) * [Wq | Wdown] + [bq | bdown]
  gemm_bt<4, true><<<(1280 / 128) * (M_TOK / 128), 256, 0, stream>>>(
      (const void*)x, WqT, bq, (void*)Qb, tab, M_TOK, 1280, D_MODEL, bdown, (void*)Lb);

  // G2: KV = latent*Wup + bup, RoPE on even 64-col blocks (gemm8p, EPI 2)
  gemm8p<2, 2 * D_MODEL, D_LATENT><<<(M_TOK / 256) * (2 * D_MODEL / 256), 512, 0, stream>>>(
      Lb, WuT, bup, (void*)KVb, tab);

  // attention
  attn_kernel<<<M_TOK / 4, 256, 0, stream>>>(Qb, KVb, Ab);

  // G3: out = att*Wout + bout, f32 (gemm8p, EPI 3)
  gemm8p<3, D_MODEL, D_MODEL><<<(M_TOK / 256) * (D_MODEL / 256), 512, 0, stream>>>(
      Ab, WoT, bout, d_out, tab);
}

// Round 11
// 207.286 us; speedup vs baseline: 1.1342x; 1.1342x over previous
//
#include <hip/hip_runtime.h>

// ---------------- problem constants ----------------
#define D_MODEL   1024
#define N_HEADS   16
#define D_LATENT  256
#define HEAD_DIM  64
#define SEQ_T     4096
#define BATCH     4
#define M_TOK     (BATCH * SEQ_T)   // 16384

typedef __attribute__((ext_vector_type(8))) short          short8;
typedef __attribute__((ext_vector_type(4))) float          f32x4;
typedef __attribute__((ext_vector_type(8))) unsigned short u16x8;

static __device__ __forceinline__ float b2f(unsigned short u) {
  unsigned x = ((unsigned)u) << 16;
  float f;
  __builtin_memcpy(&f, &x, 4);
  return f;
}
static __device__ __forceinline__ unsigned short f2b(float f) {
  unsigned x;
  __builtin_memcpy(&x, &f, 4);
  x += 0x7fffu + ((x >> 16) & 1u);   // round-to-nearest-even
  return (unsigned short)(x >> 16);
}

static __device__ __forceinline__ void gload_lds16(const unsigned short* g, unsigned short* l) {
  __builtin_amdgcn_global_load_lds(
      (const __attribute__((address_space(1))) unsigned int*)g,
      (__attribute__((address_space(3))) unsigned int*)l, 16, 0, 0);
}

#define BAR()    __builtin_amdgcn_s_barrier()
#define LGKM0()  asm volatile("s_waitcnt lgkmcnt(0)" ::: "memory")
#define LGKM8()  asm volatile("s_waitcnt lgkmcnt(8)" ::: "memory")
#define VMCNT6() asm volatile("s_waitcnt vmcnt(6)" ::: "memory")
#define VMCNT0() asm volatile("s_waitcnt vmcnt(0)" ::: "memory")

// =====================================================================
// prep_kernel: rope table + all 4 weight transposes in ONE dispatch
// (blockIdx-range dispatch; each block takes a uniform path).
//   [0,512)     rope tab  (4096x32 float2)
//   [512,1536)  Wq    1024x1024 -> WqT
//   [1536,1792) Wdown 1024x256  -> WdT
//   [1792,2304) Wup   256x2048  -> WuT
//   [2304,3328) Wout  1024x1024 -> WoT
// =====================================================================
__global__ __launch_bounds__(256) void prep_kernel(float2* __restrict__ tab,
                                                   const float* __restrict__ Wq,
                                                   unsigned short* __restrict__ WqT,
                                                   const float* __restrict__ Wdown,
                                                   unsigned short* __restrict__ WdT,
                                                   const float* __restrict__ Wup,
                                                   unsigned short* __restrict__ WuT,
                                                   const float* __restrict__ Wout,
                                                   unsigned short* __restrict__ WoT) {
  __shared__ float tile[32][33];
  const int b = blockIdx.x;
  if (b < 512) {
    const int idx = b * 256 + threadIdx.x;   // < 4096*32
    const int t = idx >> 5, j = idx & 31;
    float invf = powf(10000.f, -(float)j * (1.f / 32.f));
    float ang = (float)t * invf;
    float s, c;
    sincosf(ang, &s, &c);
    tab[idx] = make_float2(c, s);
    return;
  }
  const float* src;
  unsigned short* dst;
  int K, N, bx, by;
  if (b < 1536)      { src = Wq;    dst = WqT; K = 1024; N = 1024; const int r = b - 512;  bx = r & 31; by = r >> 5; }
  else if (b < 1792) { src = Wdown; dst = WdT; K = 1024; N = 256;  const int r = b - 1536; bx = r & 7;  by = r >> 3; }
  else if (b < 2304) { src = Wup;   dst = WuT; K = 256;  N = 2048; const int r = b - 1792; bx = r & 63; by = r >> 6; }
  else               { src = Wout;  dst = WoT; K = 1024; N = 1024; const int r = b - 2304; bx = r & 31; by = r >> 5; }
  const int tx = threadIdx.x & 31, ty = threadIdx.x >> 5;
  const int nb = bx * 32, kb = by * 32;
#pragma unroll
  for (int j = 0; j < 4; ++j)
    tile[ty + 8 * j][tx] = src[(size_t)(kb + ty + 8 * j) * N + nb + tx];
  __syncthreads();
#pragma unroll
  for (int j = 0; j < 4; ++j)
    dst[(size_t)(nb + ty + 8 * j) * K + kb + tx] = f2b(tile[tx][ty + 8 * j]);
}

// ---------------- f32 -> bf16 convert (8 elems/thread) ----------------
__global__ void cvt_kernel(const float* __restrict__ src, unsigned short* __restrict__ dst, int n8) {
  int i = blockIdx.x * blockDim.x + threadIdx.x;
  if (i >= n8) return;
  const float4* s = (const float4*)(src + (size_t)i * 8);
  float4 a = s[0], b = s[1];
  u16x8 o;
  o[0] = f2b(a.x); o[1] = f2b(a.y); o[2] = f2b(a.z); o[3] = f2b(a.w);
  o[4] = f2b(b.x); o[5] = f2b(b.y); o[6] = f2b(b.z); o[7] = f2b(b.w);
  *(u16x8*)(dst + (size_t)i * 8) = o;
}

// =====================================================================
// gemm_bt (r8 measured-best): 128x128 tile, 4 waves, BK=64, 2-barrier loop,
// gload_lds staging, scatter epilogue.
// EPI 4 = FUSED Q|latent: colB<1024 -> RoPE -> Cout (Qb, stride 1024),
//         colB>=1024 -> plain+bias2 -> Cout2 (Lb, stride 256, col-1024).
// =====================================================================
template <int EPI>
__global__ __launch_bounds__(256) void gemm_bt(const unsigned short* __restrict__ A,
                                               const unsigned short* __restrict__ Bt,
                                               const float* __restrict__ bias,
                                               void* __restrict__ Cout,
                                               const float2* __restrict__ tab,
                                               int M, int N, int K,
                                               const float* __restrict__ bias2,
                                               void* __restrict__ Cout2) {
  __shared__ unsigned short As[128 * 64];
  __shared__ unsigned short Bs[128 * 64];
  const int tid = threadIdx.x;
  const int lane = tid & 63;
  const int wid = tid >> 6;
  const int wr = wid >> 1, wc = wid & 1;
  const int l15 = lane & 15, kg = lane >> 4;

  const int gx = N >> 7;
  const int nwg = gridDim.x;
  const int q8 = nwg >> 3;
  const int bid = blockIdx.x;
  const int sid = (bid & 7) * q8 + (bid >> 3);
  const int bx = sid % gx;
  const int by = sid / gx;
  const long mBase = (long)by * 128;
  const long nBase = (long)bx * 128;

  f32x4 acc[4][4];
#pragma unroll
  for (int m = 0; m < 4; ++m)
#pragma unroll
    for (int n = 0; n < 4; ++n) {
      acc[m][n][0] = 0.f; acc[m][n][1] = 0.f; acc[m][n][2] = 0.f; acc[m][n][3] = 0.f;
    }

  for (int kt = 0; kt < K; kt += 64) {
#pragma unroll
    for (int i = 0; i < 4; ++i) {
      const int flatB = i * 4096 + tid * 16;
      const int row = flatB >> 7;
      const int kb = (flatB & 127) ^ ((row & 7) << 4);
      gload_lds16(A + (size_t)(mBase + row) * K + kt + (kb >> 1),
                  (unsigned short*)((char*)As + flatB));
      gload_lds16(Bt + (size_t)(nBase + row) * K + kt + (kb >> 1),
                  (unsigned short*)((char*)Bs + flatB));
    }
    __syncthreads();
#pragma unroll
    for (int ks = 0; ks < 2; ++ks) {
      short8 af[4], bfr[4];
      const int koff = ks * 64 + kg * 16;
#pragma unroll
      for (int m = 0; m < 4; ++m) {
        const int row = wr * 64 + m * 16 + l15;
        af[m] = *(const short8*)((const char*)As + row * 128 + (koff ^ ((row & 7) << 4)));
      }
#pragma unroll
      for (int n = 0; n < 4; ++n) {
        const int row = wc * 64 + n * 16 + l15;
        bfr[n] = *(const short8*)((const char*)Bs + row * 128 + (koff ^ ((row & 7) << 4)));
      }
#pragma unroll
      for (int m = 0; m < 4; ++m)
#pragma unroll
        for (int n = 0; n < 4; ++n)
          acc[m][n] = __builtin_amdgcn_mfma_f32_16x16x32_bf16(af[m], bfr[n], acc[m][n], 0, 0, 0);
    }
    __syncthreads();
  }

  // ---------------- epilogue (r8 scatter version) ----------------
  const int colB = (int)nBase + wc * 64;
  const long rowB = mBase + (long)wr * 64;
  const bool doRope = (EPI == 1) || (EPI == 2 && (((colB >> 6) & 1) == 0)) ||
                      (EPI == 4 && colB < 1024);

  if (doRope) {
    const int cstride = (EPI == 4) ? 1024 : N;
#pragma unroll
    for (int p = 0; p < 2; ++p) {
      const int c1 = colB + p * 16 + l15;
      const int c2 = c1 + 32;
      const float b1 = bias[c1], b2 = bias[c2];
      const int j = p * 16 + l15;  // freq index 0..31 (colB is 64-aligned)
#pragma unroll
      for (int m = 0; m < 4; ++m) {
#pragma unroll
        for (int i = 0; i < 4; ++i) {
          const long row = rowB + m * 16 + kg * 4 + i;
          const int tt = (int)(row & (SEQ_T - 1));
          const float2 cs = tab[tt * 32 + j];
          const float x1 = acc[m][p][i] + b1;
          const float x2 = acc[m][p + 2][i] + b2;
          ((unsigned short*)Cout)[row * cstride + c1] = f2b(x1 * cs.x - x2 * cs.y);
          ((unsigned short*)Cout)[row * cstride + c2] = f2b(x1 * cs.y + x2 * cs.x);
        }
      }
    }
  } else if (EPI == 4) {
    // latent rows of the fused GEMM -> Lb, stride 256
#pragma unroll
    for (int n = 0; n < 4; ++n) {
      const int col = colB + n * 16 + l15 - 1024;
      const float bb = bias2[col];
#pragma unroll
      for (int m = 0; m < 4; ++m) {
#pragma unroll
        for (int i = 0; i < 4; ++i) {
          const long row = rowB + m * 16 + kg * 4 + i;
          ((unsigned short*)Cout2)[row * 256 + col] = f2b(acc[m][n][i] + bb);
        }
      }
    }
  } else {
#pragma unroll
    for (int n = 0; n < 4; ++n) {
      const int col = colB + n * 16 + l15;
      const float bb = bias[col];
#pragma unroll
      for (int m = 0; m < 4; ++m) {
#pragma unroll
        for (int i = 0; i < 4; ++i) {
          const long row = rowB + m * 16 + kg * 4 + i;
          ((unsigned short*)Cout)[row * N + col] = f2b(acc[m][n][i] + bb);
        }
      }
    }
  }
  (void)M;
}

// =====================================================================
// gemm8p (r5 measured-best): 256x256, 8 waves, BK=64, 8-phase counted-vmcnt.
// EPI: 2 = RoPE even 64-col blocks (K of KV), bf16 out; 3 = f32 out.
// =====================================================================
template <int EPI, int NN, int KK>
__global__ __launch_bounds__(512) void gemm8p(const unsigned short* __restrict__ A,
                                              const unsigned short* __restrict__ Bt,
                                              const float* __restrict__ bias,
                                              void* __restrict__ Cout,
                                              const float2* __restrict__ tab) {
  __shared__ unsigned short As[2][16384];
  __shared__ unsigned short Bs[2][16384];
  const int tid = threadIdx.x;
  const int lane = tid & 63;
  const int wid = tid >> 6;
  const int wm = wid >> 2;
  const int wn = wid & 3;
  const int l15 = lane & 15, kg = lane >> 4;

  constexpr int gx = NN >> 8;
  const int q8 = (int)gridDim.x >> 3;
  const int bid = (int)blockIdx.x;
  const int sid = (bid & 7) * q8 + (bid >> 3);
  const long mBase = (long)(sid / gx) * 256;
  const long nBase = (long)(sid % gx) * 256;

  constexpr int nt = KK >> 6;

  const int r0 = tid >> 3;
  const int cb = (tid & 7) * 16;
  const int scb = cb ^ ((r0 & 7) << 4);
  const unsigned short* gA = A + (mBase + r0) * KK + (scb >> 1);
  const unsigned short* gB = Bt + (nBase + r0) * KK + (scb >> 1);
  const int dOff = tid << 3;

  auto stA = [&](int h, int t, int buf) __attribute__((always_inline)) {
#pragma unroll
    for (int j = 0; j < 2; ++j)
      gload_lds16(gA + (size_t)(h * 128 + j * 64) * KK + t * 64,
                  &As[buf][h * 8192 + j * 4096 + dOff]);
  };
  auto stB = [&](int h, int t, int buf) __attribute__((always_inline)) {
#pragma unroll
    for (int j = 0; j < 2; ++j)
      gload_lds16(gB + (size_t)(h * 128 + j * 64) * KK + t * 64,
                  &Bs[buf][h * 8192 + j * 4096 + dOff]);
  };

  f32x4 acc[8][4];
#pragma unroll
  for (int m = 0; m < 8; ++m)
#pragma unroll
    for (int n = 0; n < 4; ++n) {
      acc[m][n][0] = 0.f; acc[m][n][1] = 0.f; acc[m][n][2] = 0.f; acc[m][n][3] = 0.f;
    }

  stA(0, 0, 0); stA(1, 0, 0); stB(0, 0, 0); stB(1, 0, 0);
  stB(0, 1, 1); stB(1, 1, 1); stA(0, 1, 1);
  VMCNT6();
  BAR();

  auto ktile = [&](int t, int cur) __attribute__((always_inline)) {
    const char* sa = (const char*)&As[cur][0];
    const char* sb = (const char*)&Bs[cur][0];
    short8 a[4][2], b[4][2];

    // phase 0
#pragma unroll
    for (int m = 0; m < 4; ++m) {
      const int row = wm * 128 + m * 16 + l15, sw = (row & 7) << 4;
      a[m][0] = *(const short8*)(sa + row * 128 + ((kg * 16) ^ sw));
      a[m][1] = *(const short8*)(sa + row * 128 + ((64 + kg * 16) ^ sw));
    }
#pragma unroll
    for (int n = 0; n < 2; ++n) {
      const int row = wn * 64 + n * 16 + l15, sw = (row & 7) << 4;
      b[n][0] = *(const short8*)(sb + row * 128 + ((kg * 16) ^ sw));
      b[n][1] = *(const short8*)(sb + row * 128 + ((64 + kg * 16) ^ sw));
    }
    if (t + 1 < nt) stA(1, t + 1, cur ^ 1);
    LGKM8();
    BAR(); LGKM0();
    __builtin_amdgcn_s_setprio(1);
#pragma unroll
    for (int m = 0; m < 4; ++m)
#pragma unroll
      for (int n = 0; n < 2; ++n) {
        acc[m][n] = __builtin_amdgcn_mfma_f32_16x16x32_bf16(a[m][0], b[n][0], acc[m][n], 0, 0, 0);
        acc[m][n] = __builtin_amdgcn_mfma_f32_16x16x32_bf16(a[m][1], b[n][1], acc[m][n], 0, 0, 0);
      }
    __builtin_amdgcn_s_setprio(0);
    BAR();

    // phase 1
#pragma unroll
    for (int n = 2; n < 4; ++n) {
      const int row = wn * 64 + n * 16 + l15, sw = (row & 7) << 4;
      b[n][0] = *(const short8*)(sb + row * 128 + ((kg * 16) ^ sw));
      b[n][1] = *(const short8*)(sb + row * 128 + ((64 + kg * 16) ^ sw));
    }
    BAR(); LGKM0();
    __builtin_amdgcn_s_setprio(1);
#pragma unroll
    for (int m = 0; m < 4; ++m)
#pragma unroll
      for (int n = 2; n < 4; ++n) {
        acc[m][n] = __builtin_amdgcn_mfma_f32_16x16x32_bf16(a[m][0], b[n][0], acc[m][n], 0, 0, 0);
        acc[m][n] = __builtin_amdgcn_mfma_f32_16x16x32_bf16(a[m][1], b[n][1], acc[m][n], 0, 0, 0);
      }
    __builtin_amdgcn_s_setprio(0);
    BAR();

    // phase 2
#pragma unroll
    for (int m = 0; m < 4; ++m) {
      const int row = wm * 128 + (m + 4) * 16 + l15, sw = (row & 7) << 4;
      a[m][0] = *(const short8*)(sa + row * 128 + ((kg * 16) ^ sw));
      a[m][1] = *(const short8*)(sa + row * 128 + ((64 + kg * 16) ^ sw));
    }
    if (t + 2 < nt) stB(0, t + 2, cur);
    BAR(); LGKM0();
    __builtin_amdgcn_s_setprio(1);
#pragma unroll
    for (int m = 0; m < 4; ++m)
#pragma unroll
      for (int n = 2; n < 4; ++n) {
        acc[m + 4][n] = __builtin_amdgcn_mfma_f32_16x16x32_bf16(a[m][0], b[n][0], acc[m + 4][n], 0, 0, 0);
        acc[m + 4][n] = __builtin_amdgcn_mfma_f32_16x16x32_bf16(a[m][1], b[n][1], acc[m + 4][n], 0, 0, 0);
      }
    __builtin_amdgcn_s_setprio(0);
    BAR();

    // phase 3
    if (t + 2 < nt) {
      stB(1, t + 2, cur);
      stA(0, t + 2, cur);
      VMCNT6();
    } else if (t + 1 < nt) {
      VMCNT0();
    }
    BAR();
    __builtin_amdgcn_s_setprio(1);
#pragma unroll
    for (int m = 0; m < 4; ++m)
#pragma unroll
      for (int n = 0; n < 2; ++n) {
        acc[m + 4][n] = __builtin_amdgcn_mfma_f32_16x16x32_bf16(a[m][0], b[n][0], acc[m + 4][n], 0, 0, 0);
        acc[m + 4][n] = __builtin_amdgcn_mfma_f32_16x16x32_bf16(a[m][1], b[n][1], acc[m + 4][n], 0, 0, 0);
      }
    __builtin_amdgcn_s_setprio(0);
    BAR();
  };

#pragma unroll 1
  for (int t = 0; t < nt; t += 2) {
    ktile(t, 0);
    ktile(t + 1, 1);
  }

  // epilogue
  const long rowB = mBase + (long)wm * 128;
  const int colB = (int)nBase + wn * 64;
  const bool doRope = (EPI == 2 && (((colB >> 6) & 1) == 0));

  if (doRope) {
#pragma unroll
    for (int p = 0; p < 2; ++p) {
      const int c1 = colB + p * 16 + l15;
      const int c2 = c1 + 32;
      const float b1 = bias[c1], b2 = bias[c2];
      const int j = p * 16 + l15;
#pragma unroll
      for (int m = 0; m < 8; ++m) {
#pragma unroll
        for (int i = 0; i < 4; ++i) {
          const long row = rowB + m * 16 + kg * 4 + i;
          const int tt = (int)(row & (SEQ_T - 1));
          const float2 cs = tab[tt * 32 + j];
          const float x1 = acc[m][p][i] + b1;
          const float x2 = acc[m][p + 2][i] + b2;
          ((unsigned short*)Cout)[row * NN + c1] = f2b(x1 * cs.x - x2 * cs.y);
          ((unsigned short*)Cout)[row * NN + c2] = f2b(x1 * cs.y + x2 * cs.x);
        }
      }
    }
  } else {
#pragma unroll
    for (int n = 0; n < 4; ++n) {
      const int col = colB + n * 16 + l15;
      const float bb = bias[col];
#pragma unroll
      for (int m = 0; m < 8; ++m) {
#pragma unroll
        for (int i = 0; i < 4; ++i) {
          const long row = rowB + m * 16 + kg * 4 + i;
          const float v = acc[m][n][i] + bb;
          if (EPI == 3)
            ((float*)Cout)[row * NN + col] = v;
          else
            ((unsigned short*)Cout)[row * NN + col] = f2b(v);
        }
      }
    }
  }
  (void)tab;
}

// ---------------- per-token head-vs-head attention ----------------
__global__ __launch_bounds__(256) void attn_kernel(const unsigned short* __restrict__ Qb,
                                                   const unsigned short* __restrict__ KVb,
                                                   unsigned short* __restrict__ Ab) {
  __shared__ float sm[4 * 3 * 16 * 68];
  const int tid = threadIdx.x;
  const int w = tid >> 6, lane = tid & 63;
  const long token = (long)blockIdx.x * 4 + w;
  float* qs = &sm[w * (3 * 16 * 68)];
  float* ks = qs + 16 * 68;
  float* vs = ks + 16 * 68;

  {
    const u16x8* qg = (const u16x8*)(Qb + token * 1024 + lane * 16);
    u16x8 a0 = qg[0], a1 = qg[1];
    const int h = lane >> 2, d0 = (lane & 3) * 16;
    float tmp[16];
#pragma unroll
    for (int j = 0; j < 8; ++j) { tmp[j] = b2f(a0[j]); tmp[8 + j] = b2f(a1[j]); }
    float4* dst = (float4*)&qs[h * 68 + d0];
#pragma unroll
    for (int v = 0; v < 4; ++v) dst[v] = *(float4*)&tmp[4 * v];
  }
  {
    const u16x8* kg = (const u16x8*)(KVb + token * 2048 + lane * 32);
    u16x8 c0 = kg[0], c1 = kg[1], c2 = kg[2], c3 = kg[3];
    const int h = lane >> 2, part = lane & 3;
    float tmp[32];
#pragma unroll
    for (int j = 0; j < 8; ++j) {
      tmp[j] = b2f(c0[j]); tmp[8 + j] = b2f(c1[j]);
      tmp[16 + j] = b2f(c2[j]); tmp[24 + j] = b2f(c3[j]);
    }
    float* dst = (part < 2) ? &ks[h * 68 + part * 32] : &vs[h * 68 + (part - 2) * 32];
    float4* d4 = (float4*)dst;
#pragma unroll
    for (int v = 0; v < 8; ++v) d4[v] = *(float4*)&tmp[4 * v];
  }
  __syncthreads();

  const int h = lane >> 2, b = lane & 3;
  float s[4];
#pragma unroll
  for (int a = 0; a < 4; ++a) {
    const int g = 4 * a + b;
    const float4* qr = (const float4*)&qs[h * 68];
    const float4* kr = (const float4*)&ks[g * 68];
    float accv = 0.f;
#pragma unroll
    for (int t = 0; t < 16; ++t) {
      float4 qv = qr[t], kv = kr[t];
      accv += qv.x * kv.x + qv.y * kv.y + qv.z * kv.z + qv.w * kv.w;
    }
    s[a] = accv * 0.125f;
  }
  float mx = fmaxf(fmaxf(s[0], s[1]), fmaxf(s[2], s[3]));
  mx = fmaxf(mx, __shfl_xor(mx, 1, 64));
  mx = fmaxf(mx, __shfl_xor(mx, 2, 64));
  float e[4], sum = 0.f;
#pragma unroll
  for (int a = 0; a < 4; ++a) { e[a] = __expf(s[a] - mx); sum += e[a]; }
  sum += __shfl_xor(sum, 1, 64);
  sum += __shfl_xor(sum, 2, 64);
  const float rinv = 1.f / sum;
  float p[4];
#pragma unroll
  for (int a = 0; a < 4; ++a) p[a] = e[a] * rinv;

  float pf[16];
  const int qbase = lane & ~3;
#pragma unroll
  for (int bb = 0; bb < 4; ++bb)
#pragma unroll
    for (int a = 0; a < 4; ++a) pf[4 * a + bb] = __shfl(p[a], qbase + bb, 64);

#pragma unroll
  for (int k16 = 0; k16 < 16; ++k16) {
    const int d = b + 4 * k16;
    float o = 0.f;
#pragma unroll
    for (int g = 0; g < 16; ++g) o += pf[g] * vs[g * 68 + d];
    Ab[token * 1024 + h * 64 + d] = f2b(o);
  }
}

// ---------------- workspace layout (bytes) ----------------
#define OFF_TAB  0UL
#define OFF_XB   1048576UL
#define OFF_WQT  34603008UL      // WqT (1024x1024) ...
#define OFF_WDT  36700160UL      // ... contiguous with WdT (256x1024): fused 1280xK B
#define OFF_WUT  37224448UL
#define OFF_WOT  38273024UL
#define OFF_QB   40370176UL
#define OFF_LB   73924608UL
#define OFF_KVB  82313216UL
#define WS_NEEDED 149422080UL
#define OFF_AB   OFF_XB   // X dead after fused GEMM; attention output reuses it

extern "C" void kernel_launch(void* const* d_in, const int* in_sizes, int n_in,
                              void* d_out, int out_size, void* d_ws, size_t ws_size,
                              hipStream_t stream) {
  (void)in_sizes; (void)n_in; (void)out_size;
  if (ws_size < WS_NEEDED) return;

  const float* x     = (const float*)d_in[0];
  const float* Wq    = (const float*)d_in[1];
  const float* bq    = (const float*)d_in[2];
  const float* Wdown = (const float*)d_in[3];
  const float* bdown = (const float*)d_in[4];
  const float* Wup   = (const float*)d_in[5];
  const float* bup   = (const float*)d_in[6];
  const float* Wout  = (const float*)d_in[7];
  const float* bout  = (const float*)d_in[8];

  char* ws = (char*)d_ws;
  float2*         tab = (float2*)(ws + OFF_TAB);
  unsigned short* Xb  = (unsigned short*)(ws + OFF_XB);
  unsigned short* WqT = (unsigned short*)(ws + OFF_WQT);
  unsigned short* WdT = (unsigned short*)(ws + OFF_WDT);
  unsigned short* WuT = (unsigned short*)(ws + OFF_WUT);
  unsigned short* WoT = (unsigned short*)(ws + OFF_WOT);
  unsigned short* Qb  = (unsigned short*)(ws + OFF_QB);
  unsigned short* Lb  = (unsigned short*)(ws + OFF_LB);
  unsigned short* KVb = (unsigned short*)(ws + OFF_KVB);
  unsigned short* Ab  = (unsigned short*)(ws + OFF_AB);

  // prep: rope table + all 4 weight transposes (one dispatch)
  prep_kernel<<<3328, 256, 0, stream>>>(tab, Wq, WqT, Wdown, WdT, Wup, WuT, Wout, WoT);
  // x -> bf16
  cvt_kernel<<<(M_TOK * D_MODEL / 8 + 255) / 256, 256, 0, stream>>>(x, Xb, M_TOK * D_MODEL / 8);

  // G1: fused [Q | latent] = X * [Wq | Wdown] + [bq | bdown]  (r8 measured-best)
  gemm_bt<4><<<(1280 / 128) * (M_TOK / 128), 256, 0, stream>>>(
      Xb, WqT, bq, (void*)Qb, tab, M_TOK, 1280, D_MODEL, bdown, (void*)Lb);

  // G2: KV = latent*Wup + bup, RoPE on even 64-col blocks (gemm8p, r5 measured-best)
  gemm8p<2, 2 * D_MODEL, D_LATENT><<<(M_TOK / 256) * (2 * D_MODEL / 256), 512, 0, stream>>>(
      Lb, WuT, bup, (void*)KVb, tab);

  // attention
  attn_kernel<<<M_TOK / 4, 256, 0, stream>>>(Qb, KVb, Ab);

  // G3: out = att*Wout + bout, f32 (gemm8p, EPI 3)
  gemm8p<3, D_MODEL, D_MODEL><<<(M_TOK / 256) * (D_MODEL / 256), 512, 0, stream>>>(
      Ab, WoT, bout, d_out, tab);
}

// Round 12
// 205.477 us; speedup vs baseline: 1.1442x; 1.0088x over previous
//
#include <hip/hip_runtime.h>

// ---------------- problem constants ----------------
#define D_MODEL   1024
#define N_HEADS   16
#define D_LATENT  256
#define HEAD_DIM  64
#define SEQ_T     4096
#define BATCH     4
#define M_TOK     (BATCH * SEQ_T)   // 16384

typedef __attribute__((ext_vector_type(8))) short          short8;
typedef __attribute__((ext_vector_type(4))) float          f32x4;
typedef __attribute__((ext_vector_type(8))) unsigned short u16x8;

static __device__ __forceinline__ float b2f(unsigned short u) {
  unsigned x = ((unsigned)u) << 16;
  float f;
  __builtin_memcpy(&f, &x, 4);
  return f;
}
static __device__ __forceinline__ unsigned short f2b(float f) {
  unsigned x;
  __builtin_memcpy(&x, &f, 4);
  x += 0x7fffu + ((x >> 16) & 1u);   // round-to-nearest-even
  return (unsigned short)(x >> 16);
}

static __device__ __forceinline__ void gload_lds16(const unsigned short* g, unsigned short* l) {
  __builtin_amdgcn_global_load_lds(
      (const __attribute__((address_space(1))) unsigned int*)g,
      (__attribute__((address_space(3))) unsigned int*)l, 16, 0, 0);
}

#define BAR()    __builtin_amdgcn_s_barrier()
#define LGKM0()  asm volatile("s_waitcnt lgkmcnt(0)" ::: "memory")
#define LGKM8()  asm volatile("s_waitcnt lgkmcnt(8)" ::: "memory")
#define VMCNT6() asm volatile("s_waitcnt vmcnt(6)" ::: "memory")
#define VMCNT0() asm volatile("s_waitcnt vmcnt(0)" ::: "memory")

// =====================================================================
// prep_kernel: rope table + 4 weight transposes + x f32->bf16 convert,
// ALL in one dispatch (blockIdx-range dispatch; whole-block-uniform paths).
//   [0,512)       rope tab  (4096x32 float2)
//   [512,1536)    Wq    1024x1024 -> WqT
//   [1536,1792)   Wdown 1024x256  -> WdT
//   [1792,2304)   Wup   256x2048  -> WuT
//   [2304,3328)   Wout  1024x1024 -> WoT
//   [3328,11520)  x f32 -> Xb bf16 (2048 elems/block)
// =====================================================================
__global__ __launch_bounds__(256) void prep_kernel(float2* __restrict__ tab,
                                                   const float* __restrict__ Wq,
                                                   unsigned short* __restrict__ WqT,
                                                   const float* __restrict__ Wdown,
                                                   unsigned short* __restrict__ WdT,
                                                   const float* __restrict__ Wup,
                                                   unsigned short* __restrict__ WuT,
                                                   const float* __restrict__ Wout,
                                                   unsigned short* __restrict__ WoT,
                                                   const float* __restrict__ x,
                                                   unsigned short* __restrict__ Xb) {
  __shared__ float tile[32][33];
  const int b = blockIdx.x;
  if (b >= 3328) {   // x -> bf16, 8 elems/thread
    const size_t i = (size_t)(b - 3328) * 256 + threadIdx.x;
    const float4* s = (const float4*)(x + i * 8);
    float4 a = s[0], c = s[1];
    u16x8 o;
    o[0] = f2b(a.x); o[1] = f2b(a.y); o[2] = f2b(a.z); o[3] = f2b(a.w);
    o[4] = f2b(c.x); o[5] = f2b(c.y); o[6] = f2b(c.z); o[7] = f2b(c.w);
    *(u16x8*)(Xb + i * 8) = o;
    return;
  }
  if (b < 512) {
    const int idx = b * 256 + threadIdx.x;   // < 4096*32
    const int t = idx >> 5, j = idx & 31;
    float invf = powf(10000.f, -(float)j * (1.f / 32.f));
    float ang = (float)t * invf;
    float s, c;
    sincosf(ang, &s, &c);
    tab[idx] = make_float2(c, s);
    return;
  }
  const float* src;
  unsigned short* dst;
  int K, N, bx, by;
  if (b < 1536)      { src = Wq;    dst = WqT; K = 1024; N = 1024; const int r = b - 512;  bx = r & 31; by = r >> 5; }
  else if (b < 1792) { src = Wdown; dst = WdT; K = 1024; N = 256;  const int r = b - 1536; bx = r & 7;  by = r >> 3; }
  else if (b < 2304) { src = Wup;   dst = WuT; K = 256;  N = 2048; const int r = b - 1792; bx = r & 63; by = r >> 6; }
  else               { src = Wout;  dst = WoT; K = 1024; N = 1024; const int r = b - 2304; bx = r & 31; by = r >> 5; }
  const int tx = threadIdx.x & 31, ty = threadIdx.x >> 5;
  const int nb = bx * 32, kb = by * 32;
#pragma unroll
  for (int j = 0; j < 4; ++j)
    tile[ty + 8 * j][tx] = src[(size_t)(kb + ty + 8 * j) * N + nb + tx];
  __syncthreads();
#pragma unroll
  for (int j = 0; j < 4; ++j)
    dst[(size_t)(nb + ty + 8 * j) * K + kb + tx] = f2b(tile[tx][ty + 8 * j]);
}

// =====================================================================
// gemm_bt (r8 measured-best): 128x128 tile, 4 waves, BK=64, 2-barrier loop,
// gload_lds staging, scatter epilogue.
// EPI 4 = FUSED Q|latent: colB<1024 -> RoPE -> Cout (Qb, stride 1024),
//         colB>=1024 -> plain+bias2 -> Cout2 (Lb, stride 256, col-1024).
// =====================================================================
template <int EPI>
__global__ __launch_bounds__(256) void gemm_bt(const unsigned short* __restrict__ A,
                                               const unsigned short* __restrict__ Bt,
                                               const float* __restrict__ bias,
                                               void* __restrict__ Cout,
                                               const float2* __restrict__ tab,
                                               int M, int N, int K,
                                               const float* __restrict__ bias2,
                                               void* __restrict__ Cout2) {
  __shared__ unsigned short As[128 * 64];
  __shared__ unsigned short Bs[128 * 64];
  const int tid = threadIdx.x;
  const int lane = tid & 63;
  const int wid = tid >> 6;
  const int wr = wid >> 1, wc = wid & 1;
  const int l15 = lane & 15, kg = lane >> 4;

  const int gx = N >> 7;
  const int nwg = gridDim.x;
  const int q8 = nwg >> 3;
  const int bid = blockIdx.x;
  const int sid = (bid & 7) * q8 + (bid >> 3);
  const int bx = sid % gx;
  const int by = sid / gx;
  const long mBase = (long)by * 128;
  const long nBase = (long)bx * 128;

  f32x4 acc[4][4];
#pragma unroll
  for (int m = 0; m < 4; ++m)
#pragma unroll
    for (int n = 0; n < 4; ++n) {
      acc[m][n][0] = 0.f; acc[m][n][1] = 0.f; acc[m][n][2] = 0.f; acc[m][n][3] = 0.f;
    }

  for (int kt = 0; kt < K; kt += 64) {
#pragma unroll
    for (int i = 0; i < 4; ++i) {
      const int flatB = i * 4096 + tid * 16;
      const int row = flatB >> 7;
      const int kb = (flatB & 127) ^ ((row & 7) << 4);
      gload_lds16(A + (size_t)(mBase + row) * K + kt + (kb >> 1),
                  (unsigned short*)((char*)As + flatB));
      gload_lds16(Bt + (size_t)(nBase + row) * K + kt + (kb >> 1),
                  (unsigned short*)((char*)Bs + flatB));
    }
    __syncthreads();
#pragma unroll
    for (int ks = 0; ks < 2; ++ks) {
      short8 af[4], bfr[4];
      const int koff = ks * 64 + kg * 16;
#pragma unroll
      for (int m = 0; m < 4; ++m) {
        const int row = wr * 64 + m * 16 + l15;
        af[m] = *(const short8*)((const char*)As + row * 128 + (koff ^ ((row & 7) << 4)));
      }
#pragma unroll
      for (int n = 0; n < 4; ++n) {
        const int row = wc * 64 + n * 16 + l15;
        bfr[n] = *(const short8*)((const char*)Bs + row * 128 + (koff ^ ((row & 7) << 4)));
      }
#pragma unroll
      for (int m = 0; m < 4; ++m)
#pragma unroll
        for (int n = 0; n < 4; ++n)
          acc[m][n] = __builtin_amdgcn_mfma_f32_16x16x32_bf16(af[m], bfr[n], acc[m][n], 0, 0, 0);
    }
    __syncthreads();
  }

  // ---------------- epilogue (r8 scatter version) ----------------
  const int colB = (int)nBase + wc * 64;
  const long rowB = mBase + (long)wr * 64;
  const bool doRope = (EPI == 1) || (EPI == 2 && (((colB >> 6) & 1) == 0)) ||
                      (EPI == 4 && colB < 1024);

  if (doRope) {
    const int cstride = (EPI == 4) ? 1024 : N;
#pragma unroll
    for (int p = 0; p < 2; ++p) {
      const int c1 = colB + p * 16 + l15;
      const int c2 = c1 + 32;
      const float b1 = bias[c1], b2 = bias[c2];
      const int j = p * 16 + l15;  // freq index 0..31 (colB is 64-aligned)
#pragma unroll
      for (int m = 0; m < 4; ++m) {
#pragma unroll
        for (int i = 0; i < 4; ++i) {
          const long row = rowB + m * 16 + kg * 4 + i;
          const int tt = (int)(row & (SEQ_T - 1));
          const float2 cs = tab[tt * 32 + j];
          const float x1 = acc[m][p][i] + b1;
          const float x2 = acc[m][p + 2][i] + b2;
          ((unsigned short*)Cout)[row * cstride + c1] = f2b(x1 * cs.x - x2 * cs.y);
          ((unsigned short*)Cout)[row * cstride + c2] = f2b(x1 * cs.y + x2 * cs.x);
        }
      }
    }
  } else if (EPI == 4) {
    // latent rows of the fused GEMM -> Lb, stride 256
#pragma unroll
    for (int n = 0; n < 4; ++n) {
      const int col = colB + n * 16 + l15 - 1024;
      const float bb = bias2[col];
#pragma unroll
      for (int m = 0; m < 4; ++m) {
#pragma unroll
        for (int i = 0; i < 4; ++i) {
          const long row = rowB + m * 16 + kg * 4 + i;
          ((unsigned short*)Cout2)[row * 256 + col] = f2b(acc[m][n][i] + bb);
        }
      }
    }
  } else {
#pragma unroll
    for (int n = 0; n < 4; ++n) {
      const int col = colB + n * 16 + l15;
      const float bb = bias[col];
#pragma unroll
      for (int m = 0; m < 4; ++m) {
#pragma unroll
        for (int i = 0; i < 4; ++i) {
          const long row = rowB + m * 16 + kg * 4 + i;
          ((unsigned short*)Cout)[row * N + col] = f2b(acc[m][n][i] + bb);
        }
      }
    }
  }
  (void)M;
}

// =====================================================================
// gemm8p (r5 measured-best): 256x256, 8 waves, BK=64, 8-phase counted-vmcnt.
// EPI: 2 = RoPE even 64-col blocks (K of KV), bf16 out; 3 = f32 out.
// =====================================================================
template <int EPI, int NN, int KK>
__global__ __launch_bounds__(512) void gemm8p(const unsigned short* __restrict__ A,
                                              const unsigned short* __restrict__ Bt,
                                              const float* __restrict__ bias,
                                              void* __restrict__ Cout,
                                              const float2* __restrict__ tab) {
  __shared__ unsigned short As[2][16384];
  __shared__ unsigned short Bs[2][16384];
  const int tid = threadIdx.x;
  const int lane = tid & 63;
  const int wid = tid >> 6;
  const int wm = wid >> 2;
  const int wn = wid & 3;
  const int l15 = lane & 15, kg = lane >> 4;

  constexpr int gx = NN >> 8;
  const int q8 = (int)gridDim.x >> 3;
  const int bid = (int)blockIdx.x;
  const int sid = (bid & 7) * q8 + (bid >> 3);
  const long mBase = (long)(sid / gx) * 256;
  const long nBase = (long)(sid % gx) * 256;

  constexpr int nt = KK >> 6;

  const int r0 = tid >> 3;
  const int cb = (tid & 7) * 16;
  const int scb = cb ^ ((r0 & 7) << 4);
  const unsigned short* gA = A + (mBase + r0) * KK + (scb >> 1);
  const unsigned short* gB = Bt + (nBase + r0) * KK + (scb >> 1);
  const int dOff = tid << 3;

  auto stA = [&](int h, int t, int buf) __attribute__((always_inline)) {
#pragma unroll
    for (int j = 0; j < 2; ++j)
      gload_lds16(gA + (size_t)(h * 128 + j * 64) * KK + t * 64,
                  &As[buf][h * 8192 + j * 4096 + dOff]);
  };
  auto stB = [&](int h, int t, int buf) __attribute__((always_inline)) {
#pragma unroll
    for (int j = 0; j < 2; ++j)
      gload_lds16(gB + (size_t)(h * 128 + j * 64) * KK + t * 64,
                  &Bs[buf][h * 8192 + j * 4096 + dOff]);
  };

  f32x4 acc[8][4];
#pragma unroll
  for (int m = 0; m < 8; ++m)
#pragma unroll
    for (int n = 0; n < 4; ++n) {
      acc[m][n][0] = 0.f; acc[m][n][1] = 0.f; acc[m][n][2] = 0.f; acc[m][n][3] = 0.f;
    }

  stA(0, 0, 0); stA(1, 0, 0); stB(0, 0, 0); stB(1, 0, 0);
  stB(0, 1, 1); stB(1, 1, 1); stA(0, 1, 1);
  VMCNT6();
  BAR();

  auto ktile = [&](int t, int cur) __attribute__((always_inline)) {
    const char* sa = (const char*)&As[cur][0];
    const char* sb = (const char*)&Bs[cur][0];
    short8 a[4][2], b[4][2];

    // phase 0
#pragma unroll
    for (int m = 0; m < 4; ++m) {
      const int row = wm * 128 + m * 16 + l15, sw = (row & 7) << 4;
      a[m][0] = *(const short8*)(sa + row * 128 + ((kg * 16) ^ sw));
      a[m][1] = *(const short8*)(sa + row * 128 + ((64 + kg * 16) ^ sw));
    }
#pragma unroll
    for (int n = 0; n < 2; ++n) {
      const int row = wn * 64 + n * 16 + l15, sw = (row & 7) << 4;
      b[n][0] = *(const short8*)(sb + row * 128 + ((kg * 16) ^ sw));
      b[n][1] = *(const short8*)(sb + row * 128 + ((64 + kg * 16) ^ sw));
    }
    if (t + 1 < nt) stA(1, t + 1, cur ^ 1);
    LGKM8();
    BAR(); LGKM0();
    __builtin_amdgcn_s_setprio(1);
#pragma unroll
    for (int m = 0; m < 4; ++m)
#pragma unroll
      for (int n = 0; n < 2; ++n) {
        acc[m][n] = __builtin_amdgcn_mfma_f32_16x16x32_bf16(a[m][0], b[n][0], acc[m][n], 0, 0, 0);
        acc[m][n] = __builtin_amdgcn_mfma_f32_16x16x32_bf16(a[m][1], b[n][1], acc[m][n], 0, 0, 0);
      }
    __builtin_amdgcn_s_setprio(0);
    BAR();

    // phase 1
#pragma unroll
    for (int n = 2; n < 4; ++n) {
      const int row = wn * 64 + n * 16 + l15, sw = (row & 7) << 4;
      b[n][0] = *(const short8*)(sb + row * 128 + ((kg * 16) ^ sw));
      b[n][1] = *(const short8*)(sb + row * 128 + ((64 + kg * 16) ^ sw));
    }
    BAR(); LGKM0();
    __builtin_amdgcn_s_setprio(1);
#pragma unroll
    for (int m = 0; m < 4; ++m)
#pragma unroll
      for (int n = 2; n < 4; ++n) {
        acc[m][n] = __builtin_amdgcn_mfma_f32_16x16x32_bf16(a[m][0], b[n][0], acc[m][n], 0, 0, 0);
        acc[m][n] = __builtin_amdgcn_mfma_f32_16x16x32_bf16(a[m][1], b[n][1], acc[m][n], 0, 0, 0);
      }
    __builtin_amdgcn_s_setprio(0);
    BAR();

    // phase 2
#pragma unroll
    for (int m = 0; m < 4; ++m) {
      const int row = wm * 128 + (m + 4) * 16 + l15, sw = (row & 7) << 4;
      a[m][0] = *(const short8*)(sa + row * 128 + ((kg * 16) ^ sw));
      a[m][1] = *(const short8*)(sa + row * 128 + ((64 + kg * 16) ^ sw));
    }
    if (t + 2 < nt) stB(0, t + 2, cur);
    BAR(); LGKM0();
    __builtin_amdgcn_s_setprio(1);
#pragma unroll
    for (int m = 0; m < 4; ++m)
#pragma unroll
      for (int n = 2; n < 4; ++n) {
        acc[m + 4][n] = __builtin_amdgcn_mfma_f32_16x16x32_bf16(a[m][0], b[n][0], acc[m + 4][n], 0, 0, 0);
        acc[m + 4][n] = __builtin_amdgcn_mfma_f32_16x16x32_bf16(a[m][1], b[n][1], acc[m + 4][n], 0, 0, 0);
      }
    __builtin_amdgcn_s_setprio(0);
    BAR();

    // phase 3
    if (t + 2 < nt) {
      stB(1, t + 2, cur);
      stA(0, t + 2, cur);
      VMCNT6();
    } else if (t + 1 < nt) {
      VMCNT0();
    }
    BAR();
    __builtin_amdgcn_s_setprio(1);
#pragma unroll
    for (int m = 0; m < 4; ++m)
#pragma unroll
      for (int n = 0; n < 2; ++n) {
        acc[m + 4][n] = __builtin_amdgcn_mfma_f32_16x16x32_bf16(a[m][0], b[n][0], acc[m + 4][n], 0, 0, 0);
        acc[m + 4][n] = __builtin_amdgcn_mfma_f32_16x16x32_bf16(a[m][1], b[n][1], acc[m + 4][n], 0, 0, 0);
      }
    __builtin_amdgcn_s_setprio(0);
    BAR();
  };

#pragma unroll 1
  for (int t = 0; t < nt; t += 2) {
    ktile(t, 0);
    ktile(t + 1, 1);
  }

  // epilogue
  const long rowB = mBase + (long)wm * 128;
  const int colB = (int)nBase + wn * 64;
  const bool doRope = (EPI == 2 && (((colB >> 6) & 1) == 0));

  if (doRope) {
#pragma unroll
    for (int p = 0; p < 2; ++p) {
      const int c1 = colB + p * 16 + l15;
      const int c2 = c1 + 32;
      const float b1 = bias[c1], b2 = bias[c2];
      const int j = p * 16 + l15;
#pragma unroll
      for (int m = 0; m < 8; ++m) {
#pragma unroll
        for (int i = 0; i < 4; ++i) {
          const long row = rowB + m * 16 + kg * 4 + i;
          const int tt = (int)(row & (SEQ_T - 1));
          const float2 cs = tab[tt * 32 + j];
          const float x1 = acc[m][p][i] + b1;
          const float x2 = acc[m][p + 2][i] + b2;
          ((unsigned short*)Cout)[row * NN + c1] = f2b(x1 * cs.x - x2 * cs.y);
          ((unsigned short*)Cout)[row * NN + c2] = f2b(x1 * cs.y + x2 * cs.x);
        }
      }
    }
  } else {
#pragma unroll
    for (int n = 0; n < 4; ++n) {
      const int col = colB + n * 16 + l15;
      const float bb = bias[col];
#pragma unroll
      for (int m = 0; m < 8; ++m) {
#pragma unroll
        for (int i = 0; i < 4; ++i) {
          const long row = rowB + m * 16 + kg * 4 + i;
          const float v = acc[m][n][i] + bb;
          if (EPI == 3)
            ((float*)Cout)[row * NN + col] = v;
          else
            ((unsigned short*)Cout)[row * NN + col] = f2b(v);
        }
      }
    }
  }
  (void)tab;
}

// ---------------- per-token head-vs-head attention ----------------
__global__ __launch_bounds__(256) void attn_kernel(const unsigned short* __restrict__ Qb,
                                                   const unsigned short* __restrict__ KVb,
                                                   unsigned short* __restrict__ Ab) {
  __shared__ float sm[4 * 3 * 16 * 68];
  const int tid = threadIdx.x;
  const int w = tid >> 6, lane = tid & 63;
  const long token = (long)blockIdx.x * 4 + w;
  float* qs = &sm[w * (3 * 16 * 68)];
  float* ks = qs + 16 * 68;
  float* vs = ks + 16 * 68;

  {
    const u16x8* qg = (const u16x8*)(Qb + token * 1024 + lane * 16);
    u16x8 a0 = qg[0], a1 = qg[1];
    const int h = lane >> 2, d0 = (lane & 3) * 16;
    float tmp[16];
#pragma unroll
    for (int j = 0; j < 8; ++j) { tmp[j] = b2f(a0[j]); tmp[8 + j] = b2f(a1[j]); }
    float4* dst = (float4*)&qs[h * 68 + d0];
#pragma unroll
    for (int v = 0; v < 4; ++v) dst[v] = *(float4*)&tmp[4 * v];
  }
  {
    const u16x8* kg = (const u16x8*)(KVb + token * 2048 + lane * 32);
    u16x8 c0 = kg[0], c1 = kg[1], c2 = kg[2], c3 = kg[3];
    const int h = lane >> 2, part = lane & 3;
    float tmp[32];
#pragma unroll
    for (int j = 0; j < 8; ++j) {
      tmp[j] = b2f(c0[j]); tmp[8 + j] = b2f(c1[j]);
      tmp[16 + j] = b2f(c2[j]); tmp[24 + j] = b2f(c3[j]);
    }
    float* dst = (part < 2) ? &ks[h * 68 + part * 32] : &vs[h * 68 + (part - 2) * 32];
    float4* d4 = (float4*)dst;
#pragma unroll
    for (int v = 0; v < 8; ++v) d4[v] = *(float4*)&tmp[4 * v];
  }
  __syncthreads();

  const int h = lane >> 2, b = lane & 3;
  float s[4];
#pragma unroll
  for (int a = 0; a < 4; ++a) {
    const int g = 4 * a + b;
    const float4* qr = (const float4*)&qs[h * 68];
    const float4* kr = (const float4*)&ks[g * 68];
    float accv = 0.f;
#pragma unroll
    for (int t = 0; t < 16; ++t) {
      float4 qv = qr[t], kv = kr[t];
      accv += qv.x * kv.x + qv.y * kv.y + qv.z * kv.z + qv.w * kv.w;
    }
    s[a] = accv * 0.125f;
  }
  float mx = fmaxf(fmaxf(s[0], s[1]), fmaxf(s[2], s[3]));
  mx = fmaxf(mx, __shfl_xor(mx, 1, 64));
  mx = fmaxf(mx, __shfl_xor(mx, 2, 64));
  float e[4], sum = 0.f;
#pragma unroll
  for (int a = 0; a < 4; ++a) { e[a] = __expf(s[a] - mx); sum += e[a]; }
  sum += __shfl_xor(sum, 1, 64);
  sum += __shfl_xor(sum, 2, 64);
  const float rinv = 1.f / sum;
  float p[4];
#pragma unroll
  for (int a = 0; a < 4; ++a) p[a] = e[a] * rinv;

  float pf[16];
  const int qbase = lane & ~3;
#pragma unroll
  for (int bb = 0; bb < 4; ++bb)
#pragma unroll
    for (int a = 0; a < 4; ++a) pf[4 * a + bb] = __shfl(p[a], qbase + bb, 64);

#pragma unroll
  for (int k16 = 0; k16 < 16; ++k16) {
    const int d = b + 4 * k16;
    float o = 0.f;
#pragma unroll
    for (int g = 0; g < 16; ++g) o += pf[g] * vs[g * 68 + d];
    Ab[token * 1024 + h * 64 + d] = f2b(o);
  }
}

// ---------------- workspace layout (bytes) ----------------
#define OFF_TAB  0UL
#define OFF_XB   1048576UL
#define OFF_WQT  34603008UL      // WqT (1024x1024) ...
#define OFF_WDT  36700160UL      // ... contiguous with WdT (256x1024): fused 1280xK B
#define OFF_WUT  37224448UL
#define OFF_WOT  38273024UL
#define OFF_QB   40370176UL
#define OFF_LB   73924608UL
#define OFF_KVB  82313216UL
#define WS_NEEDED 149422080UL
#define OFF_AB   OFF_XB   // X dead after fused GEMM; attention output reuses it

extern "C" void kernel_launch(void* const* d_in, const int* in_sizes, int n_in,
                              void* d_out, int out_size, void* d_ws, size_t ws_size,
                              hipStream_t stream) {
  (void)in_sizes; (void)n_in; (void)out_size;
  if (ws_size < WS_NEEDED) return;

  const float* x     = (const float*)d_in[0];
  const float* Wq    = (const float*)d_in[1];
  const float* bq    = (const float*)d_in[2];
  const float* Wdown = (const float*)d_in[3];
  const float* bdown = (const float*)d_in[4];
  const float* Wup   = (const float*)d_in[5];
  const float* bup   = (const float*)d_in[6];
  const float* Wout  = (const float*)d_in[7];
  const float* bout  = (const float*)d_in[8];

  char* ws = (char*)d_ws;
  float2*         tab = (float2*)(ws + OFF_TAB);
  unsigned short* Xb  = (unsigned short*)(ws + OFF_XB);
  unsigned short* WqT = (unsigned short*)(ws + OFF_WQT);
  unsigned short* WdT = (unsigned short*)(ws + OFF_WDT);
  unsigned short* WuT = (unsigned short*)(ws + OFF_WUT);
  unsigned short* WoT = (unsigned short*)(ws + OFF_WOT);
  unsigned short* Qb  = (unsigned short*)(ws + OFF_QB);
  unsigned short* Lb  = (unsigned short*)(ws + OFF_LB);
  unsigned short* KVb = (unsigned short*)(ws + OFF_KVB);
  unsigned short* Ab  = (unsigned short*)(ws + OFF_AB);

  // prep: rope table + 4 weight transposes + x->bf16 convert, ONE dispatch
  prep_kernel<<<11520, 256, 0, stream>>>(tab, Wq, WqT, Wdown, WdT, Wup, WuT,
                                         Wout, WoT, x, Xb);

  // G1: fused [Q | latent] = X * [Wq | Wdown] + [bq | bdown]  (r8 measured-best)
  gemm_bt<4><<<(1280 / 128) * (M_TOK / 128), 256, 0, stream>>>(
      Xb, WqT, bq, (void*)Qb, tab, M_TOK, 1280, D_MODEL, bdown, (void*)Lb);

  // G2: KV = latent*Wup + bup, RoPE on even 64-col blocks (gemm8p, r5 measured-best)
  gemm8p<2, 2 * D_MODEL, D_LATENT><<<(M_TOK / 256) * (2 * D_MODEL / 256), 512, 0, stream>>>(
      Lb, WuT, bup, (void*)KVb, tab);

  // attention
  attn_kernel<<<M_TOK / 4, 256, 0, stream>>>(Qb, KVb, Ab);

  // G3: out = att*Wout + bout, f32 (gemm8p, EPI 3)
  gemm8p<3, D_MODEL, D_MODEL><<<(M_TOK / 256) * (D_MODEL / 256), 512, 0, stream>>>(
      Ab, WoT, bout, d_out, tab);
}